// Round 11
// baseline (185.495 us; speedup 1.0000x reference)
//
#include <hip/hip_runtime.h>
#include <stdint.h>

#define M_DIM 2048
#define K_DIM 4096
#define N_DIM 11008

typedef int v4i  __attribute__((ext_vector_type(4)));
typedef int v16i __attribute__((ext_vector_type(16)));

// ---------------- workspace layout ----------------
// xq_packed: [mblk=16][kt=64][u=512]x16B  (8 MB)  fragment-ordered
// wt_packed: [nblk=43][kt=64][u=1024]x16B (45 MB)
#define WS_XQ_OFF   65536ull
#define WS_WT_OFF   8454144ull
#define WS_FULL_BYTES (8454144ull + 45088768ull)
#define WS_SMALL_BYTES 8454144ull

static __device__ __forceinline__ void llds16(const void* g, void* l) {
  __builtin_amdgcn_global_load_lds(
      reinterpret_cast<const uint32_t __attribute__((address_space(1)))*>(
          reinterpret_cast<uintptr_t>(g)),
      reinterpret_cast<uint32_t __attribute__((address_space(3)))*>(
          reinterpret_cast<uintptr_t>(l)),
      16, 0, 0);
}

// ---------------- kernel 1: per-block abs-max over x ----------------
__global__ __launch_bounds__(256) void absmax_kernel(const float* __restrict__ x,
                                                     float* __restrict__ part) {
  __shared__ float red[256];
  const int g = blockIdx.x * 256 + threadIdx.x;
  const float4* x4 = reinterpret_cast<const float4*>(x);
  float m = 0.f;
#pragma unroll
  for (int i = 0; i < 8; ++i) {
    float4 v = x4[(size_t)i * 262144 + g];
    m = fmaxf(m, fmaxf(fmaxf(fabsf(v.x), fabsf(v.y)),
                       fmaxf(fabsf(v.z), fabsf(v.w))));
  }
  red[threadIdx.x] = m;
  __syncthreads();
  for (int s = 128; s > 0; s >>= 1) {
    if (threadIdx.x < s) red[threadIdx.x] = fmaxf(red[threadIdx.x], red[threadIdx.x + s]);
    __syncthreads();
  }
  if (threadIdx.x == 0) part[blockIdx.x] = red[0];
}

// ---------------- kernel 2: finalize scales ----------------
__global__ __launch_bounds__(256) void finalize_scale(const float* __restrict__ part,
                                                      const float* __restrict__ y_scale,
                                                      float* __restrict__ scales) {
  __shared__ float red[256];
  const int t = threadIdx.x;
  float m = fmaxf(fmaxf(part[t], part[t + 256]), fmaxf(part[t + 512], part[t + 768]));
  red[t] = m;
  __syncthreads();
  for (int s = 128; s > 0; s >>= 1) {
    if (t < s) red[t] = fmaxf(red[t], red[t + s]);
    __syncthreads();
  }
  if (t == 0) {
    float xs = red[0] * (1.0f / 128.0f);  // exact (pow2)
    scales[0] = xs;
    scales[1] = xs * y_scale[0];
  }
}

static __device__ __forceinline__ int quant4(float4 v, float s) {
  int q0 = (int)rintf(v.x / s);  // matches np.round (half-to-even)
  int q1 = (int)rintf(v.y / s);
  int q2 = (int)rintf(v.z / s);
  int q3 = (int)rintf(v.w / s);
  q0 = max(-128, min(127, q0));
  q1 = max(-128, min(127, q1));
  q2 = max(-128, min(127, q2));
  q3 = max(-128, min(127, q3));
  return (q0 & 255) | ((q1 & 255) << 8) | ((q2 & 255) << 16) | ((q3 & 255) << 24);
}

// ---------------- kernel 3a: quantize x -> xq_packed (fragment order) --------
// Unit u (16B) within [mblk][kt]: u = (rowgrp<<7)|(kstep<<6)|(khalf<<5)|row32.
__global__ __launch_bounds__(256) void quant_pack(const float* __restrict__ x,
                                                  const float* __restrict__ scales,
                                                  signed char* __restrict__ xq) {
  const float s = scales[0];
  const int g = blockIdx.x * 256 + threadIdx.x;   // unit id, 524288 total
  const int mblk = g >> 15;
  const int kt = (g >> 9) & 63;
  const int u = g & 511;
  const int row = mblk * 128 + ((u >> 7) & 3) * 32 + (u & 31);
  const int kf = kt * 64 + ((u >> 6) & 1) * 32 + ((u >> 5) & 1) * 16;
  const float4* xp = reinterpret_cast<const float4*>(x + (size_t)row * K_DIM + kf);
  v4i o;
#pragma unroll
  for (int i = 0; i < 4; ++i) o[i] = quant4(xp[i], s);
  *reinterpret_cast<v4i*>(xq + (size_t)g * 16) = o;
}

// ---------------- kernel 3b: row-major quant (fallback path only) ------------
__global__ __launch_bounds__(256) void quant_rowmajor(const float* __restrict__ x,
                                                      const float* __restrict__ scales,
                                                      signed char* __restrict__ xq) {
  const float s = scales[0];
  const size_t t = (size_t)blockIdx.x * 256 + threadIdx.x;
  const float4* x4 = reinterpret_cast<const float4*>(x) + t * 4;
  v4i o;
#pragma unroll
  for (int i = 0; i < 4; ++i) o[i] = quant4(x4[i], s);
  *reinterpret_cast<v4i*>(xq + t * 16) = o;
}

// ---------------- kernel 4: transpose+pack w32[K,N] -> wt_packed --------------
// Unit u within [nblk][kt]: u = (ngrp<<7)|(kstep<<6)|(khalf<<5)|n32.
__global__ __launch_bounds__(256) void transpose_pack(const int* __restrict__ w,
                                                      signed char* __restrict__ wt) {
  __shared__ int tile[64 * 65];  // [k][n], pad 65
  const int t = threadIdx.x;
  const int bx = blockIdx.x;          // n-tile (64 cols)
  const int by = blockIdx.y;          // k-tile (64 rows)
  const int n0 = bx * 64;
  const int k0 = by * 64;
#pragma unroll
  for (int p = 0; p < 4; ++p) {
    const int id = p * 256 + t;
    const int r = id >> 4;
    const int c4 = id & 15;
    v4i v = *reinterpret_cast<const v4i*>(w + (size_t)(k0 + r) * N_DIM + n0 + c4 * 4);
    tile[r * 65 + c4 * 4 + 0] = v[0];
    tile[r * 65 + c4 * 4 + 1] = v[1];
    tile[r * 65 + c4 * 4 + 2] = v[2];
    tile[r * 65 + c4 * 4 + 3] = v[3];
  }
  __syncthreads();
  const int nl = ((t >> 7) << 5) | (t & 31);
  const int kc = (t >> 5) & 3;
  v4i o;
#pragma unroll
  for (int q = 0; q < 4; ++q) {
    const int kb = kc * 16 + q * 4;
    int b0 = tile[(kb + 0) * 65 + nl] & 255;
    int b1 = tile[(kb + 1) * 65 + nl] & 255;
    int b2 = tile[(kb + 2) * 65 + nl] & 255;
    int b3 = tile[(kb + 3) * 65 + nl] & 255;
    o[q] = b0 | (b1 << 8) | (b2 << 16) | (b3 << 24);
  }
  const size_t base = ((size_t)(bx >> 2) * 64 + by) * 16384;   // [nblk][kt]
  const int ubase = ((bx & 3) * 2) << 7;                        // ngrp_base*128
  *reinterpret_cast<v4i*>(wt + base + (size_t)(ubase + t) * 16) = o;
}

// ---------------- kernel 5: int8 MFMA GEMM v11 (register-direct, no LDS) ------
// 688 blocks x 256 thr (4 waves). Block = 256m x 128n; wave = 64m x 128n via
// 2x4 frags of mfma_i32_32x32x32_i8. All operands loaded DIRECTLY global->VGPR
// (packed fragment order: each frag = contiguous 16B at base+lane*16).
// NO LDS, NO barriers -> nothing to drain; explicit 2-deep named-register
// pipeline gives the compiler the AITER-style MFMA<->load interleave with
// counted vmcnt (it waits on outstanding counts, never 0 mid-loop).
// The 4 waves share each K-tile's 8KB B slice -> L1/L2 hits.
__global__ __launch_bounds__(256, 2) void gemm_i8_v11(
    const signed char* __restrict__ xq, const signed char* __restrict__ wt,
    const float* __restrict__ scales, const float* __restrict__ bias,
    float* __restrict__ y) {
  const int tid = threadIdx.x;
  const int lane = tid & 63;
  const int w = tid >> 6;            // wave 0..3 -> 64-row slice of 256

  // XCD swizzle (688 = 8 x 86, bijective), mblk-fastest: 8 consecutive swz
  // share one 128-col B panel (XCD-local), covering all of A.
  const int bid = blockIdx.x;
  const int swz = (bid & 7) * 86 + (bid >> 3);
  const int bm = swz & 7;            // 8 m-blocks of 256 rows
  const int bn = swz >> 3;           // 86 n-blocks of 128 cols

  // A: wave rows = bm*256 + w*64 -> packed mblk = bm*2 + (w>>1), grp base (w&1)*2
  const int amblk = bm * 2 + (w >> 1);
  const int agrp0 = (w & 1) * 2;
  const signed char* gA = xq + (size_t)amblk * 64 * 8192 + agrp0 * 2048 + lane * 16;
  // B: cols = bn*128 -> packed nblk = bn>>1, grp base (bn&1)*4
  const signed char* gB = wt + (size_t)(bn >> 1) * 64 * 16384 + (bn & 1) * 4 * 2048
                             + lane * 16;

#define LOADK(kt, A0, A1, A2, A3, B0, B1, B2, B3, B4, B5, B6, B7)              \
  do {                                                                         \
    const signed char* pa_ = gA + (size_t)(kt) * 8192;                         \
    const signed char* pb_ = gB + (size_t)(kt) * 16384;                        \
    A0 = *reinterpret_cast<const v4i*>(pa_);          /* fa0 ks0 */            \
    A1 = *reinterpret_cast<const v4i*>(pa_ + 1024);   /* fa0 ks1 */            \
    A2 = *reinterpret_cast<const v4i*>(pa_ + 2048);   /* fa1 ks0 */            \
    A3 = *reinterpret_cast<const v4i*>(pa_ + 3072);   /* fa1 ks1 */            \
    B0 = *reinterpret_cast<const v4i*>(pb_);                                   \
    B1 = *reinterpret_cast<const v4i*>(pb_ + 1024);                            \
    B2 = *reinterpret_cast<const v4i*>(pb_ + 2048);                            \
    B3 = *reinterpret_cast<const v4i*>(pb_ + 3072);                            \
    B4 = *reinterpret_cast<const v4i*>(pb_ + 4096);                            \
    B5 = *reinterpret_cast<const v4i*>(pb_ + 5120);                            \
    B6 = *reinterpret_cast<const v4i*>(pb_ + 6144);                            \
    B7 = *reinterpret_cast<const v4i*>(pb_ + 7168);                            \
  } while (0)

#define COMPK(A0, A1, A2, A3, B0, B1, B2, B3, B4, B5, B6, B7)                  \
  do {                                                                         \
    acc[0][0] = __builtin_amdgcn_mfma_i32_32x32x32_i8(A0, B0, acc[0][0], 0, 0, 0); \
    acc[0][1] = __builtin_amdgcn_mfma_i32_32x32x32_i8(A0, B2, acc[0][1], 0, 0, 0); \
    acc[0][2] = __builtin_amdgcn_mfma_i32_32x32x32_i8(A0, B4, acc[0][2], 0, 0, 0); \
    acc[0][3] = __builtin_amdgcn_mfma_i32_32x32x32_i8(A0, B6, acc[0][3], 0, 0, 0); \
    acc[1][0] = __builtin_amdgcn_mfma_i32_32x32x32_i8(A2, B0, acc[1][0], 0, 0, 0); \
    acc[1][1] = __builtin_amdgcn_mfma_i32_32x32x32_i8(A2, B2, acc[1][1], 0, 0, 0); \
    acc[1][2] = __builtin_amdgcn_mfma_i32_32x32x32_i8(A2, B4, acc[1][2], 0, 0, 0); \
    acc[1][3] = __builtin_amdgcn_mfma_i32_32x32x32_i8(A2, B6, acc[1][3], 0, 0, 0); \
    acc[0][0] = __builtin_amdgcn_mfma_i32_32x32x32_i8(A1, B1, acc[0][0], 0, 0, 0); \
    acc[0][1] = __builtin_amdgcn_mfma_i32_32x32x32_i8(A1, B3, acc[0][1], 0, 0, 0); \
    acc[0][2] = __builtin_amdgcn_mfma_i32_32x32x32_i8(A1, B5, acc[0][2], 0, 0, 0); \
    acc[0][3] = __builtin_amdgcn_mfma_i32_32x32x32_i8(A1, B7, acc[0][3], 0, 0, 0); \
    acc[1][0] = __builtin_amdgcn_mfma_i32_32x32x32_i8(A3, B1, acc[1][0], 0, 0, 0); \
    acc[1][1] = __builtin_amdgcn_mfma_i32_32x32x32_i8(A3, B3, acc[1][1], 0, 0, 0); \
    acc[1][2] = __builtin_amdgcn_mfma_i32_32x32x32_i8(A3, B5, acc[1][2], 0, 0, 0); \
    acc[1][3] = __builtin_amdgcn_mfma_i32_32x32x32_i8(A3, B7, acc[1][3], 0, 0, 0); \
  } while (0)

  v16i acc[2][4] = {};
  // two named register sets (rule #20: no runtime-indexed buffers)
  v4i xa0, xa1, xa2, xa3, xb0, xb1, xb2, xb3, xb4, xb5, xb6, xb7;  // set X
  v4i ya0, ya1, ya2, ya3, yb0, yb1, yb2, yb3, yb4, yb5, yb6, yb7;  // set Y

  LOADK(0, xa0, xa1, xa2, xa3, xb0, xb1, xb2, xb3, xb4, xb5, xb6, xb7);
  for (int t = 0; t < 62; t += 2) {
    LOADK(t + 1, ya0, ya1, ya2, ya3, yb0, yb1, yb2, yb3, yb4, yb5, yb6, yb7);
    COMPK(xa0, xa1, xa2, xa3, xb0, xb1, xb2, xb3, xb4, xb5, xb6, xb7);
    LOADK(t + 2, xa0, xa1, xa2, xa3, xb0, xb1, xb2, xb3, xb4, xb5, xb6, xb7);
    COMPK(ya0, ya1, ya2, ya3, yb0, yb1, yb2, yb3, yb4, yb5, yb6, yb7);
  }
  // set X holds kt=62
  LOADK(63, ya0, ya1, ya2, ya3, yb0, yb1, yb2, yb3, yb4, yb5, yb6, yb7);
  COMPK(xa0, xa1, xa2, xa3, xb0, xb1, xb2, xb3, xb4, xb5, xb6, xb7);
  COMPK(ya0, ya1, ya2, ya3, yb0, yb1, yb2, yb3, yb4, yb5, yb6, yb7);

#undef LOADK
#undef COMPK

  // epilogue: 32x32 C/D layout col=lane&31, row=(reg&3)+8*(reg>>2)+4*(lane>>5)
  // [measured m74/m101; R8/R9/R10 refcheck-passed]
  const float s = scales[1];
  const int l31 = lane & 31;
  const int lh4 = (lane >> 5) * 4;
  const int row0 = bm * 256 + w * 64;
  const int col0 = bn * 128;
#pragma unroll
  for (int fb = 0; fb < 4; ++fb) {
    const int col = col0 + fb * 32 + l31;
    const float bv = bias[col];
#pragma unroll
    for (int fa = 0; fa < 2; ++fa) {
      const int rbase = row0 + fa * 32 + lh4;
#pragma unroll
      for (int reg = 0; reg < 16; ++reg) {
        const int row = rbase + (reg & 3) + 8 * (reg >> 2);
        y[(size_t)row * N_DIM + col] = (float)acc[fa][fb][reg] * s + bv;
      }
    }
  }
}

// ---------------- fallback (small ws): sdot4 LDS GEMM reading w32 ----------------
#if defined(__has_builtin)
#if __has_builtin(__builtin_amdgcn_sdot4)
#define HAVE_SDOT4 1
#endif
#endif

static __device__ __forceinline__ int dot4(int a, int b, int c) {
#ifdef HAVE_SDOT4
  return __builtin_amdgcn_sdot4(a, b, c, false);
#else
  c += (int)(signed char)(a) * (int)(signed char)(b);
  c += (int)(signed char)(a >> 8) * (int)(signed char)(b >> 8);
  c += (int)(signed char)(a >> 16) * (int)(signed char)(b >> 16);
  c += (int)(signed char)(a >> 24) * (int)(signed char)(b >> 24);
  return c;
#endif
}

__global__ __launch_bounds__(256) void gemm_fallback(
    const signed char* __restrict__ xq, const int* __restrict__ w,
    const float* __restrict__ scales, const float* __restrict__ bias,
    float* __restrict__ y) {
  __shared__ int lds_a[64 * 17];
  __shared__ int lds_b[64 * 17];
  const int t = threadIdx.x;
  const int m0 = blockIdx.y * 64;
  const int n0 = blockIdx.x * 64;
  const int my = (t >> 4) * 4;
  const int nx = (t & 15) * 4;
  int acc[4][4] = {};
  for (int kt = 0; kt < K_DIM / 64; ++kt) {
    const int k0 = kt * 64;
    {
      const int r = t >> 2, sg = t & 3;
      v4i v = *reinterpret_cast<const v4i*>(xq + (size_t)(m0 + r) * K_DIM + k0 + sg * 16);
      lds_a[r * 17 + sg * 4 + 0] = v[0];
      lds_a[r * 17 + sg * 4 + 1] = v[1];
      lds_a[r * 17 + sg * 4 + 2] = v[2];
      lds_a[r * 17 + sg * 4 + 3] = v[3];
    }
    {
      const int n = t & 63, bkk = (t >> 6) * 4;
#pragma unroll
      for (int q = 0; q < 4; ++q) {
        const int kk = bkk + q;
        int b0 = w[(size_t)(k0 + kk * 4 + 0) * N_DIM + n0 + n] & 255;
        int b1 = w[(size_t)(k0 + kk * 4 + 1) * N_DIM + n0 + n] & 255;
        int b2 = w[(size_t)(k0 + kk * 4 + 2) * N_DIM + n0 + n] & 255;
        int b3 = w[(size_t)(k0 + kk * 4 + 3) * N_DIM + n0 + n] & 255;
        lds_b[n * 17 + kk] = b0 | (b1 << 8) | (b2 << 16) | (b3 << 24);
      }
    }
    __syncthreads();
#pragma unroll
    for (int kk = 0; kk < 16; ++kk) {
      int a[4], b[4];
#pragma unroll
      for (int i = 0; i < 4; ++i) a[i] = lds_a[(my + i) * 17 + kk];
#pragma unroll
      for (int j = 0; j < 4; ++j) b[j] = lds_b[(nx + j) * 17 + kk];
#pragma unroll
      for (int i = 0; i < 4; ++i)
#pragma unroll
        for (int j = 0; j < 4; ++j) acc[i][j] = dot4(a[i], b[j], acc[i][j]);
    }
    __syncthreads();
  }
  const float s = scales[1];
#pragma unroll
  for (int i = 0; i < 4; ++i)
#pragma unroll
    for (int j = 0; j < 4; ++j)
      y[(size_t)(m0 + my + i) * N_DIM + n0 + nx + j] =
          (float)acc[i][j] * s + bias[n0 + nx + j];
}

// ---------------- launcher ----------------
extern "C" void kernel_launch(void* const* d_in, const int* in_sizes, int n_in,
                              void* d_out, int out_size, void* d_ws, size_t ws_size,
                              hipStream_t stream) {
  (void)in_sizes; (void)n_in; (void)out_size;
  const float* x = (const float*)d_in[0];
  const int* w = (const int*)d_in[1];  // int8 values stored as int32
  const float* bias = (const float*)d_in[2];
  const float* yscale = (const float*)d_in[3];
  float* y = (float*)d_out;
  char* ws = (char*)d_ws;
  float* scales = (float*)(ws);
  float* part = (float*)(ws + 1024);
  signed char* xq = (signed char*)(ws + WS_XQ_OFF);
  signed char* wt = (signed char*)(ws + WS_WT_OFF);

  if (ws_size < WS_SMALL_BYTES) return;

  absmax_kernel<<<1024, 256, 0, stream>>>(x, part);
  finalize_scale<<<1, 256, 0, stream>>>(part, yscale, scales);
  if (ws_size >= WS_FULL_BYTES) {
    quant_pack<<<2048, 256, 0, stream>>>(x, scales, xq);
    transpose_pack<<<dim3(N_DIM / 64, K_DIM / 64), 256, 0, stream>>>(w, wt);
    gemm_i8_v11<<<688, 256, 0, stream>>>(xq, wt, scales, bias, y);
  } else {
    quant_rowmajor<<<2048, 256, 0, stream>>>(x, scales, xq);
    gemm_fallback<<<dim3(N_DIM / 64, M_DIM / 64), 256, 0, stream>>>(xq, w, scales, bias, y);
  }
}

// Round 12
// 159.067 us; speedup vs baseline: 1.1661x; 1.1661x over previous
//
#include <hip/hip_runtime.h>
#include <stdint.h>

#define M_DIM 2048
#define K_DIM 4096
#define N_DIM 11008

typedef int v4i  __attribute__((ext_vector_type(4)));
typedef int v16i __attribute__((ext_vector_type(16)));

// ---------------- workspace layout ----------------
// xq_packed: [mblk=16][kt=64][u=512]x16B  (8 MB)  fragment-ordered
// wt_packed: [nblk=43][kt=64][u=1024]x16B (45 MB)
#define WS_XQ_OFF   65536ull
#define WS_WT_OFF   8454144ull
#define WS_FULL_BYTES (8454144ull + 45088768ull)
#define WS_SMALL_BYTES 8454144ull

static __device__ __forceinline__ void llds16(const void* g, void* l) {
  __builtin_amdgcn_global_load_lds(
      reinterpret_cast<const uint32_t __attribute__((address_space(1)))*>(
          reinterpret_cast<uintptr_t>(g)),
      reinterpret_cast<uint32_t __attribute__((address_space(3)))*>(
          reinterpret_cast<uintptr_t>(l)),
      16, 0, 0);
}

// ---------------- kernel 1: per-block abs-max over x ----------------
__global__ __launch_bounds__(256) void absmax_kernel(const float* __restrict__ x,
                                                     float* __restrict__ part) {
  __shared__ float red[256];
  const int g = blockIdx.x * 256 + threadIdx.x;
  const float4* x4 = reinterpret_cast<const float4*>(x);
  float m = 0.f;
#pragma unroll
  for (int i = 0; i < 8; ++i) {
    float4 v = x4[(size_t)i * 262144 + g];
    m = fmaxf(m, fmaxf(fmaxf(fabsf(v.x), fabsf(v.y)),
                       fmaxf(fabsf(v.z), fabsf(v.w))));
  }
  red[threadIdx.x] = m;
  __syncthreads();
  for (int s = 128; s > 0; s >>= 1) {
    if (threadIdx.x < s) red[threadIdx.x] = fmaxf(red[threadIdx.x], red[threadIdx.x + s]);
    __syncthreads();
  }
  if (threadIdx.x == 0) part[blockIdx.x] = red[0];
}

// ---------------- kernel 2: finalize scales ----------------
__global__ __launch_bounds__(256) void finalize_scale(const float* __restrict__ part,
                                                      const float* __restrict__ y_scale,
                                                      float* __restrict__ scales) {
  __shared__ float red[256];
  const int t = threadIdx.x;
  float m = fmaxf(fmaxf(part[t], part[t + 256]), fmaxf(part[t + 512], part[t + 768]));
  red[t] = m;
  __syncthreads();
  for (int s = 128; s > 0; s >>= 1) {
    if (t < s) red[t] = fmaxf(red[t], red[t + s]);
    __syncthreads();
  }
  if (t == 0) {
    float xs = red[0] * (1.0f / 128.0f);  // exact (pow2)
    scales[0] = xs;
    scales[1] = xs * y_scale[0];
  }
}

static __device__ __forceinline__ int quant4(float4 v, float s) {
  int q0 = (int)rintf(v.x / s);  // matches np.round (half-to-even)
  int q1 = (int)rintf(v.y / s);
  int q2 = (int)rintf(v.z / s);
  int q3 = (int)rintf(v.w / s);
  q0 = max(-128, min(127, q0));
  q1 = max(-128, min(127, q1));
  q2 = max(-128, min(127, q2));
  q3 = max(-128, min(127, q3));
  return (q0 & 255) | ((q1 & 255) << 8) | ((q2 & 255) << 16) | ((q3 & 255) << 24);
}

// ---------------- kernel 3a: quantize x -> xq_packed (fragment order) --------
// Unit u (16B) within [mblk][kt]: u = (rowgrp<<7)|(kstep<<6)|(khalf<<5)|row32.
__global__ __launch_bounds__(256) void quant_pack(const float* __restrict__ x,
                                                  const float* __restrict__ scales,
                                                  signed char* __restrict__ xq) {
  const float s = scales[0];
  const int g = blockIdx.x * 256 + threadIdx.x;   // unit id, 524288 total
  const int mblk = g >> 15;
  const int kt = (g >> 9) & 63;
  const int u = g & 511;
  const int row = mblk * 128 + ((u >> 7) & 3) * 32 + (u & 31);
  const int kf = kt * 64 + ((u >> 6) & 1) * 32 + ((u >> 5) & 1) * 16;
  const float4* xp = reinterpret_cast<const float4*>(x + (size_t)row * K_DIM + kf);
  v4i o;
#pragma unroll
  for (int i = 0; i < 4; ++i) o[i] = quant4(xp[i], s);
  *reinterpret_cast<v4i*>(xq + (size_t)g * 16) = o;
}

// ---------------- kernel 3b: row-major quant (fallback path only) ------------
__global__ __launch_bounds__(256) void quant_rowmajor(const float* __restrict__ x,
                                                      const float* __restrict__ scales,
                                                      signed char* __restrict__ xq) {
  const float s = scales[0];
  const size_t t = (size_t)blockIdx.x * 256 + threadIdx.x;
  const float4* x4 = reinterpret_cast<const float4*>(x) + t * 4;
  v4i o;
#pragma unroll
  for (int i = 0; i < 4; ++i) o[i] = quant4(x4[i], s);
  *reinterpret_cast<v4i*>(xq + t * 16) = o;
}

// ---------------- kernel 4: transpose+pack w32[K,N] -> wt_packed --------------
// Unit u within [nblk][kt]: u = (ngrp<<7)|(kstep<<6)|(khalf<<5)|n32.
__global__ __launch_bounds__(256) void transpose_pack(const int* __restrict__ w,
                                                      signed char* __restrict__ wt) {
  __shared__ int tile[64 * 65];  // [k][n], pad 65
  const int t = threadIdx.x;
  const int bx = blockIdx.x;          // n-tile (64 cols)
  const int by = blockIdx.y;          // k-tile (64 rows)
  const int n0 = bx * 64;
  const int k0 = by * 64;
#pragma unroll
  for (int p = 0; p < 4; ++p) {
    const int id = p * 256 + t;
    const int r = id >> 4;
    const int c4 = id & 15;
    v4i v = *reinterpret_cast<const v4i*>(w + (size_t)(k0 + r) * N_DIM + n0 + c4 * 4);
    tile[r * 65 + c4 * 4 + 0] = v[0];
    tile[r * 65 + c4 * 4 + 1] = v[1];
    tile[r * 65 + c4 * 4 + 2] = v[2];
    tile[r * 65 + c4 * 4 + 3] = v[3];
  }
  __syncthreads();
  const int nl = ((t >> 7) << 5) | (t & 31);
  const int kc = (t >> 5) & 3;
  v4i o;
#pragma unroll
  for (int q = 0; q < 4; ++q) {
    const int kb = kc * 16 + q * 4;
    int b0 = tile[(kb + 0) * 65 + nl] & 255;
    int b1 = tile[(kb + 1) * 65 + nl] & 255;
    int b2 = tile[(kb + 2) * 65 + nl] & 255;
    int b3 = tile[(kb + 3) * 65 + nl] & 255;
    o[q] = b0 | (b1 << 8) | (b2 << 16) | (b3 << 24);
  }
  const size_t base = ((size_t)(bx >> 2) * 64 + by) * 16384;   // [nblk][kt]
  const int ubase = ((bx & 3) * 2) << 7;                        // ngrp_base*128
  *reinterpret_cast<v4i*>(wt + base + (size_t)(ubase + t) * 16) = o;
}

// ---------------- kernel 5: int8 MFMA GEMM v8 (32x32x32, packed operands) -----
// [R8 restored — measured optimum of the family: 100.2us, MfmaUtil 43%]
// BM=128, BN=256, BK=64 bytes. 512 threads = 8 waves (2M x 4N), wave-tile
// 64x64 via 2x2 frags of mfma_i32_32x32x32_i8. Operands pre-packed in
// fragment order: staging is 3 contiguous global_load_lds / thread; all
// ds_read_b128 are base + lane*16 (conflict-free). Ring-3 x 24KB = 72KB
// -> 2 blk/CU. Depth-2 prefetch, vmcnt(3) once per K-tile (never 0 in loop).
#define V8_TILE_B 24576           // A 8KB + B 16KB
#define V8_NT     (K_DIM / 64)    // 64 K-tiles

__global__ __launch_bounds__(512, 4) void gemm_i8_v8(
    const signed char* __restrict__ xq, const signed char* __restrict__ wt,
    const float* __restrict__ scales, const float* __restrict__ bias,
    float* __restrict__ y) {
  __shared__ __align__(16) signed char smem[3 * V8_TILE_B];  // 72 KB
  const int tid = threadIdx.x;

  // T1: bijective XCD swizzle (688 blocks = 8 x 86), column-major grid.
  const int bid = blockIdx.x;
  const int swz = (bid & 7) * 86 + (bid >> 3);
  const int mblk = swz & 15;        // 16 m-tiles of 128
  const int nblk = swz >> 4;        // 43 n-tiles of 256
  const int m0 = mblk * 128;
  const int n0 = nblk * 256;

  // staging: fragment-packed global source, contiguous per (blk, kt).
  const signed char* gA = xq + (size_t)mblk * 64 * 8192;    // + kt*8192  + tid*16
  const signed char* gB = wt + (size_t)nblk * 64 * 16384;   // + kt*16384 + tid*16 (+8192)
  signed char* const ld = smem + tid * 16;

#define STAGE(kt, soff)                                                   \
  do {                                                                    \
    llds16(gA + (size_t)(kt) * 8192 + tid * 16,         ld + (soff));     \
    llds16(gB + (size_t)(kt) * 16384 + tid * 16,        ld + (soff) + 8192);  \
    llds16(gB + (size_t)(kt) * 16384 + 8192 + tid * 16, ld + (soff) + 16384); \
  } while (0)

  // fragment map: LDS image is unit-ordered; frag (grp, kstep) lives at
  // grp*2048 + kstep*1024 + lane*16  (A: grp = wm*2+fa in [0,4); B: wn*2+fb in [0,8)).
  const int lane = tid & 63;
  const int wid = tid >> 6;
  const int wm = wid >> 2;   // 0..1
  const int wn = wid & 3;    // 0..3
  const int aoff = (wm * 2) * 2048 + lane * 16;           // + fa*2048 + ks*1024
  const int boff = 8192 + (wn * 2) * 2048 + lane * 16;    // + fb*2048 + ks*1024

  v16i acc[2][2] = {};

#define COMPUTE(roff)                                                         \
  do {                                                                        \
    const signed char* bp_ = smem + (roff);                                   \
    _Pragma("unroll")                                                         \
    for (int ks_ = 0; ks_ < 2; ++ks_) {                                       \
      v4i a0 = *reinterpret_cast<const v4i*>(bp_ + aoff + ks_ * 1024);        \
      v4i a1 = *reinterpret_cast<const v4i*>(bp_ + aoff + 2048 + ks_ * 1024); \
      v4i b0 = *reinterpret_cast<const v4i*>(bp_ + boff + ks_ * 1024);        \
      v4i b1 = *reinterpret_cast<const v4i*>(bp_ + boff + 2048 + ks_ * 1024); \
      acc[0][0] = __builtin_amdgcn_mfma_i32_32x32x32_i8(a0, b0, acc[0][0], 0, 0, 0); \
      acc[0][1] = __builtin_amdgcn_mfma_i32_32x32x32_i8(a0, b1, acc[0][1], 0, 0, 0); \
      acc[1][0] = __builtin_amdgcn_mfma_i32_32x32x32_i8(a1, b0, acc[1][0], 0, 0, 0); \
      acc[1][1] = __builtin_amdgcn_mfma_i32_32x32x32_i8(a1, b1, acc[1][1], 0, 0, 0); \
    }                                                                         \
  } while (0)

  // prologue: stage tiles 0,1 (6 loads/thread in flight); retire tile 0.
  STAGE(0, 0);
  STAGE(1, V8_TILE_B);
  asm volatile("s_waitcnt vmcnt(3)" ::: "memory");
  __builtin_amdgcn_s_barrier();

  int rOff = 0;
  int sOff = 2 * V8_TILE_B;
  for (int t = 0; t < V8_NT - 2; ++t) {
    STAGE(t + 2, sOff);              // outstanding: t+1:3, t+2:3
    COMPUTE(rOff);                   // 8 ds_read_b128 + 8 MFMA (32x32x32)
    asm volatile("s_waitcnt vmcnt(3)" ::: "memory");  // retire tile t+1
    __builtin_amdgcn_s_barrier();
    rOff = (rOff == 2 * V8_TILE_B) ? 0 : rOff + V8_TILE_B;
    sOff = (sOff == 2 * V8_TILE_B) ? 0 : sOff + V8_TILE_B;
  }
  // t = NT-2: no staging; drain remaining tile
  COMPUTE(rOff);
  asm volatile("s_waitcnt vmcnt(0)" ::: "memory");
  __builtin_amdgcn_s_barrier();
  rOff = (rOff == 2 * V8_TILE_B) ? 0 : rOff + V8_TILE_B;
  // t = NT-1: final tile
  COMPUTE(rOff);

#undef STAGE
#undef COMPUTE

  // epilogue: 32x32 C/D layout col=lane&31, row=(reg&3)+8*(reg>>2)+4*(lane>>5)
  // [measured: m74/m101, dtype-independent; R8 refcheck-passed]
  const float s = scales[1];
  const int l31 = lane & 31;
  const int lh4 = (lane >> 5) * 4;
#pragma unroll
  for (int fb = 0; fb < 2; ++fb) {
    const int col = n0 + wn * 64 + fb * 32 + l31;
    const float bv = bias[col];
#pragma unroll
    for (int fa = 0; fa < 2; ++fa) {
      const int rbase = m0 + wm * 64 + fa * 32 + lh4;
#pragma unroll
      for (int reg = 0; reg < 16; ++reg) {
        const int row = rbase + (reg & 3) + 8 * (reg >> 2);
        y[(size_t)row * N_DIM + col] = (float)acc[fa][fb][reg] * s + bv;
      }
    }
  }
}

// ---------------- fallback (small ws): sdot4 LDS GEMM reading w32 ----------------
#if defined(__has_builtin)
#if __has_builtin(__builtin_amdgcn_sdot4)
#define HAVE_SDOT4 1
#endif
#endif

static __device__ __forceinline__ int dot4(int a, int b, int c) {
#ifdef HAVE_SDOT4
  return __builtin_amdgcn_sdot4(a, b, c, false);
#else
  c += (int)(signed char)(a) * (int)(signed char)(b);
  c += (int)(signed char)(a >> 8) * (int)(signed char)(b >> 8);
  c += (int)(signed char)(a >> 16) * (int)(signed char)(b >> 16);
  c += (int)(signed char)(a >> 24) * (int)(signed char)(b >> 24);
  return c;
#endif
}

__global__ __launch_bounds__(256) void gemm_fallback(
    const signed char* __restrict__ xq, const int* __restrict__ w,
    const float* __restrict__ scales, const float* __restrict__ bias,
    float* __restrict__ y) {
  __shared__ int lds_a[64 * 17];
  __shared__ int lds_b[64 * 17];
  const int t = threadIdx.x;
  const int m0 = blockIdx.y * 64;
  const int n0 = blockIdx.x * 64;
  const int my = (t >> 4) * 4;
  const int nx = (t & 15) * 4;
  int acc[4][4] = {};
  for (int kt = 0; kt < K_DIM / 64; ++kt) {
    const int k0 = kt * 64;
    {
      const int r = t >> 2, sg = t & 3;
      v4i v = *reinterpret_cast<const v4i*>(xq + (size_t)(m0 + r) * K_DIM + k0 + sg * 16);
      lds_a[r * 17 + sg * 4 + 0] = v[0];
      lds_a[r * 17 + sg * 4 + 1] = v[1];
      lds_a[r * 17 + sg * 4 + 2] = v[2];
      lds_a[r * 17 + sg * 4 + 3] = v[3];
    }
    {
      const int n = t & 63, bkk = (t >> 6) * 4;
#pragma unroll
      for (int q = 0; q < 4; ++q) {
        const int kk = bkk + q;
        int b0 = w[(size_t)(k0 + kk * 4 + 0) * N_DIM + n0 + n] & 255;
        int b1 = w[(size_t)(k0 + kk * 4 + 1) * N_DIM + n0 + n] & 255;
        int b2 = w[(size_t)(k0 + kk * 4 + 2) * N_DIM + n0 + n] & 255;
        int b3 = w[(size_t)(k0 + kk * 4 + 3) * N_DIM + n0 + n] & 255;
        lds_b[n * 17 + kk] = b0 | (b1 << 8) | (b2 << 16) | (b3 << 24);
      }
    }
    __syncthreads();
#pragma unroll
    for (int kk = 0; kk < 16; ++kk) {
      int a[4], b[4];
#pragma unroll
      for (int i = 0; i < 4; ++i) a[i] = lds_a[(my + i) * 17 + kk];
#pragma unroll
      for (int j = 0; j < 4; ++j) b[j] = lds_b[(nx + j) * 17 + kk];
#pragma unroll
      for (int i = 0; i < 4; ++i)
#pragma unroll
        for (int j = 0; j < 4; ++j) acc[i][j] = dot4(a[i], b[j], acc[i][j]);
    }
    __syncthreads();
  }
  const float s = scales[1];
#pragma unroll
  for (int i = 0; i < 4; ++i)
#pragma unroll
    for (int j = 0; j < 4; ++j)
      y[(size_t)(m0 + my + i) * N_DIM + n0 + nx + j] =
          (float)acc[i][j] * s + bias[n0 + nx + j];
}

// ---------------- launcher ----------------
extern "C" void kernel_launch(void* const* d_in, const int* in_sizes, int n_in,
                              void* d_out, int out_size, void* d_ws, size_t ws_size,
                              hipStream_t stream) {
  (void)in_sizes; (void)n_in; (void)out_size;
  const float* x = (const float*)d_in[0];
  const int* w = (const int*)d_in[1];  // int8 values stored as int32
  const float* bias = (const float*)d_in[2];
  const float* yscale = (const float*)d_in[3];
  float* y = (float*)d_out;
  char* ws = (char*)d_ws;
  float* scales = (float*)(ws);
  float* part = (float*)(ws + 1024);
  signed char* xq = (signed char*)(ws + WS_XQ_OFF);
  signed char* wt = (signed char*)(ws + WS_WT_OFF);

  if (ws_size < WS_SMALL_BYTES) return;

  absmax_kernel<<<1024, 256, 0, stream>>>(x, part);
  finalize_scale<<<1, 256, 0, stream>>>(part, yscale, scales);
  if (ws_size >= WS_FULL_BYTES) {
    quant_pack<<<2048, 256, 0, stream>>>(x, scales, xq);
    transpose_pack<<<dim3(N_DIM / 64, K_DIM / 64), 256, 0, stream>>>(w, wt);
    gemm_i8_v8<<<(M_DIM / 128) * (N_DIM / 256), 512, 0, stream>>>(xq, wt, scales, bias, y);
  } else {
    quant_rowmajor<<<2048, 256, 0, stream>>>(x, scales, xq);
    gemm_fallback<<<dim3(N_DIM / 64, M_DIM / 64), 256, 0, stream>>>(xq, w, scales, bias, y);
  }
}